// Round 2
// baseline (355.394 us; speedup 1.0000x reference)
//
#include <hip/hip_runtime.h>
#include <math.h>

typedef float f32x4 __attribute__((ext_vector_type(4)));

#define H      4096
#define E      64
#define TOPK   8
#define TILE_T 64
#define KC     64
#define XS_STR 68
#define WT_STR 68

// fp64-accurate router: fp32 LDS staging, f64 accumulation in registers.
// 64 tokens x 64 experts per 256-thread block; 4 tok x 4 exp per thread.
// Selection (top-8) done on f64 logits -> matches exact ranking.
__global__ __launch_bounds__(256)
void moe_gate_f64(const float* __restrict__ X,
                  const float* __restrict__ Wg,
                  float* __restrict__ out, int n_tokens)
{
  __shared__ float  Xs[TILE_T * XS_STR];   // 17.4 KB
  __shared__ float  Wt[KC * WT_STR];       // 17.4 KB
  __shared__ double Ls[TILE_T * E];        // 32 KB

  const int tid = threadIdx.x;
  const int t0  = blockIdx.x * TILE_T;

  const int eg = tid & 15;   // experts 4eg..4eg+3
  const int tg = tid >> 4;   // tokens 4tg..4tg+3

  const float* Xb = X + (size_t)t0 * H;

  double acc[4][4];
  #pragma unroll
  for (int i = 0; i < 4; i++)
    #pragma unroll
    for (int j = 0; j < 4; j++) acc[i][j] = 0.0;

  f32x4 xr[4], wr[4];

  // preload chunk 0 (coalesced f32x4)
  #pragma unroll
  for (int q = 0; q < 4; q++) {
    int idx = q * 256 + tid;
    xr[q] = *(const f32x4*)(Xb + (idx >> 4) * H + ((idx & 15) << 2));
    wr[q] = *(const f32x4*)(Wg + (idx >> 4) * H + ((idx & 15) << 2));
  }

  for (int kc = 0; kc < H; kc += KC) {
    __syncthreads();
    // stage X row-major (b128)
    #pragma unroll
    for (int q = 0; q < 4; q++) {
      int idx = q * 256 + tid;
      *(f32x4*)(&Xs[(idx >> 4) * XS_STR + ((idx & 15) << 2)]) = xr[q];
    }
    // stage W transposed k-major (b32 scatter)
    #pragma unroll
    for (int q = 0; q < 4; q++) {
      int idx = q * 256 + tid;
      int e = idx >> 4, c4 = idx & 15;
      #pragma unroll
      for (int c = 0; c < 4; c++)
        Wt[(c4 * 4 + c) * WT_STR + e] = wr[q][c];
    }
    __syncthreads();

    // prefetch next chunk
    int kn = kc + KC;
    if (kn < H) {
      #pragma unroll
      for (int q = 0; q < 4; q++) {
        int idx = q * 256 + tid;
        xr[q] = *(const f32x4*)(Xb + (idx >> 4) * H + kn + ((idx & 15) << 2));
        wr[q] = *(const f32x4*)(Wg + (idx >> 4) * H + kn + ((idx & 15) << 2));
      }
    }

    // compute: per 4-k step: 16 x-cvt + 16 w-cvt + 64 f64 FMA
    #pragma unroll
    for (int ks = 0; ks < KC; ks += 4) {
      double xd[4][4];
      #pragma unroll
      for (int t = 0; t < 4; t++) {
        f32x4 xv = *(const f32x4*)(&Xs[(4 * tg + t) * XS_STR + ks]);
        #pragma unroll
        for (int c = 0; c < 4; c++) xd[t][c] = (double)xv[c];
      }
      #pragma unroll
      for (int c = 0; c < 4; c++) {
        f32x4 wv = *(const f32x4*)(&Wt[(ks + c) * WT_STR + (eg << 2)]);
        #pragma unroll
        for (int j = 0; j < 4; j++) {
          double wd = (double)wv[j];
          #pragma unroll
          for (int t = 0; t < 4; t++)
            acc[t][j] = fma(xd[t][c], wd, acc[t][j]);
        }
      }
    }
  }

  // logits (f64) -> LDS
  #pragma unroll
  for (int t = 0; t < 4; t++)
    #pragma unroll
    for (int j = 0; j < 4; j++)
      Ls[(4 * tg + t) * E + (eg << 2) + j] = acc[t][j];
  __syncthreads();

  // per-token softmax + top-8 on f64 logits (1 wave per token-slice)
  const int wave = tid >> 6;
  const int lane = tid & 63;

  for (int tt = 0; tt < TILE_T / 4; tt++) {
    int t = wave * (TILE_T / 4) + tt;
    double val = Ls[t * E + lane];

    double m = val;
    #pragma unroll
    for (int off = 32; off >= 1; off >>= 1)
      m = fmax(m, __shfl_xor(m, off));

    double p = exp(val - m);
    double S = p;
    #pragma unroll
    for (int off = 32; off >= 1; off >>= 1)
      S += __shfl_xor(S, off);

    // top-8 by logit (monotone in score), lower index wins ties
    double cur = val;
    double myw = 0.0; int myidx = 0;
    double psum = 0.0;
    #pragma unroll
    for (int r = 0; r < TOPK; r++) {
      double v = cur; int ii = lane;
      #pragma unroll
      for (int off = 32; off >= 1; off >>= 1) {
        double ov = __shfl_xor(v, off);
        int    oi = __shfl_xor(ii, off);
        if (ov > v || (ov == v && oi < ii)) { v = ov; ii = oi; }
      }
      double pw = __shfl(p, ii);
      psum += pw;
      if (lane == r) { myw = pw; myidx = ii; }
      if (lane == ii) cur = -INFINITY;
    }
    // reference: (p/S) / (sum_top8(p/S) + 1e-20)
    double denom = psum / S + 1e-20;
    if (lane < TOPK) {
      size_t gt = (size_t)(t0 + t);
      out[gt * TOPK + lane] = (float)((myw / S) / denom);
      out[(size_t)n_tokens * TOPK + gt * TOPK + lane] = (float)myidx;
    }
  }
}

extern "C" void kernel_launch(void* const* d_in, const int* in_sizes, int n_in,
                              void* d_out, int out_size, void* d_ws, size_t ws_size,
                              hipStream_t stream)
{
  const float* X  = (const float*)d_in[0];
  const float* Wg = (const float*)d_in[1];
  float* out = (float*)d_out;
  int n_tokens = in_sizes[0] / H;       // 16384
  int grid = n_tokens / TILE_T;         // 256
  moe_gate_f64<<<grid, 256, 0, stream>>>(X, Wg, out, n_tokens);
}

// Round 4
// 222.305 us; speedup vs baseline: 1.5987x; 1.5987x over previous
//
#include <hip/hip_runtime.h>
#include <math.h>

typedef float  f32x4 __attribute__((ext_vector_type(4)));
typedef double f64x4 __attribute__((ext_vector_type(4)));

#define H      4096
#define E      64
#define TOPK   8
#define TILE_T 32

// Pre-transpose W[e][k] (f32) into the order the main loop consumes:
//   Wb[ ((m*4 + kg)*64 + e)*4 + i ] = W[e][16m + 4kg + i]
__global__ __launch_bounds__(256)
void transpose_w(const float* __restrict__ Wg, float* __restrict__ Wb)
{
  int n = blockIdx.x * 256 + threadIdx.x;    // 64*4096 = 262144
  int e = n >> 12, k = n & 4095;
  float v = Wg[n];
  int m = k >> 4, kg = (k >> 2) & 3, i = k & 3;
  Wb[(((m * 4 + kg) * 64) + e) * 4 + i] = v;
}

// f64-exact router via v_mfma_f64_16x16x4_f64, with RUNTIME-PROBED fragment
// readout mapping (R3 proved values correct but labels permuted; probes make
// the labeling correct by construction for any hardware convention).
__global__ __launch_bounds__(256)
void moe_gate_mfma(const float* __restrict__ X, const float* __restrict__ Wb,
                   float* __restrict__ out, int n_tokens)
{
  __shared__ double Ls[TILE_T * E];   // 16 KB, epilogue only

  const int tid  = threadIdx.x;
  const int lane = tid & 63;
  const int w    = tid >> 6;      // wave -> expert group 16w..16w+15
  const int t0   = blockIdx.x * TILE_T;
  const int l15  = lane & 15;
  const int kg   = lane >> 4;

  // ---- probe the effective (lane,reg) -> (token,expert) readout map ----
  f64x4 z = {0.0, 0.0, 0.0, 0.0};
  f64x4 pcol = __builtin_amdgcn_mfma_f64_16x16x4f64(1.0, (double)l15, z, 0, 0, 0);
  f64x4 prow = __builtin_amdgcn_mfma_f64_16x16x4f64((double)l15, 1.0, z, 0, 0, 0);
  int qrow[4], qcol[4];
  #pragma unroll
  for (int r = 0; r < 4; ++r) {
    qrow[r] = (int)(prow[r] * 0.25 + 0.5);   // token offset fed via arg0's l15
    qcol[r] = (int)(pcol[r] * 0.25 + 0.5);   // expert offset fed via arg1's l15
  }

  const float* xp0 = X  + (size_t)(t0 + l15) * H + 4 * kg;        // tokens 0..15
  const float* xp1 = X  + (size_t)(t0 + 16 + l15) * H + 4 * kg;   // tokens 16..31
  const float* bp  = Wb + ((size_t)kg * 64 + 16 * w + l15) * 4;   // experts 16w+l15

  f64x4 c0 = {0.0, 0.0, 0.0, 0.0};
  f64x4 c1 = {0.0, 0.0, 0.0, 0.0};

  f32x4 a0 = *(const f32x4*)(xp0);
  f32x4 a1 = *(const f32x4*)(xp1);
  f32x4 bv = *(const f32x4*)(bp);

  #pragma unroll 4
  for (int m = 0; m < 255; ++m) {
    f32x4 na0 = *(const f32x4*)(xp0 + (m + 1) * 16);
    f32x4 na1 = *(const f32x4*)(xp1 + (m + 1) * 16);
    f32x4 nbv = *(const f32x4*)(bp + (size_t)(m + 1) * 1024);
    #pragma unroll
    for (int i = 0; i < 4; ++i) {
      double bd = (double)bv[i];
      c0 = __builtin_amdgcn_mfma_f64_16x16x4f64((double)a0[i], bd, c0, 0, 0, 0);
      c1 = __builtin_amdgcn_mfma_f64_16x16x4f64((double)a1[i], bd, c1, 0, 0, 0);
    }
    a0 = na0; a1 = na1; bv = nbv;
  }
  #pragma unroll
  for (int i = 0; i < 4; ++i) {
    double bd = (double)bv[i];
    c0 = __builtin_amdgcn_mfma_f64_16x16x4f64((double)a0[i], bd, c0, 0, 0, 0);
    c1 = __builtin_amdgcn_mfma_f64_16x16x4f64((double)a1[i], bd, c1, 0, 0, 0);
  }

  // C frags -> LDS logits via probed mapping
  #pragma unroll
  for (int r = 0; r < 4; ++r) {
    Ls[qrow[r] * E + 16 * w + qcol[r]]        = c0[r];
    Ls[(16 + qrow[r]) * E + 16 * w + qcol[r]] = c1[r];
  }
  __syncthreads();

  // per-token softmax + top-8 on f64 logits (verified in R2)
  for (int tt = 0; tt < TILE_T / 4; tt++) {
    int t = w * (TILE_T / 4) + tt;
    double val = Ls[t * E + lane];

    double mx = val;
    #pragma unroll
    for (int off = 32; off >= 1; off >>= 1)
      mx = fmax(mx, __shfl_xor(mx, off));

    double p = exp(val - mx);
    double S = p;
    #pragma unroll
    for (int off = 32; off >= 1; off >>= 1)
      S += __shfl_xor(S, off);

    double cur = val;
    double myw = 0.0; int myidx = 0;
    double psum = 0.0;
    #pragma unroll
    for (int r = 0; r < TOPK; r++) {
      double v = cur; int ii = lane;
      #pragma unroll
      for (int off = 32; off >= 1; off >>= 1) {
        double ov = __shfl_xor(v, off);
        int    oi = __shfl_xor(ii, off);
        if (ov > v || (ov == v && oi < ii)) { v = ov; ii = oi; }
      }
      double pw = __shfl(p, ii);
      psum += pw;
      if (lane == r) { myw = pw; myidx = ii; }
      if (lane == ii) cur = -INFINITY;
    }
    double denom = psum / S + 1e-20;
    if (lane < TOPK) {
      size_t gt = (size_t)(t0 + t);
      out[gt * TOPK + lane] = (float)((myw / S) / denom);
      out[(size_t)n_tokens * TOPK + gt * TOPK + lane] = (float)myidx;
    }
  }
}

extern "C" void kernel_launch(void* const* d_in, const int* in_sizes, int n_in,
                              void* d_out, int out_size, void* d_ws, size_t ws_size,
                              hipStream_t stream)
{
  const float* X  = (const float*)d_in[0];
  const float* Wg = (const float*)d_in[1];
  float* out = (float*)d_out;
  float* Wb  = (float*)d_ws;            // 1 MB scratch (proven intact in R3)
  int n_tokens = in_sizes[0] / H;       // 16384

  transpose_w<<<(E * H) / 256, 256, 0, stream>>>(Wg, Wb);
  moe_gate_mfma<<<n_tokens / TILE_T, 256, 0, stream>>>(X, Wb, out, n_tokens);
}

// Round 5
// 178.908 us; speedup vs baseline: 1.9865x; 1.2426x over previous
//
#include <hip/hip_runtime.h>
#include <math.h>

typedef float  f32x4 __attribute__((ext_vector_type(4)));
typedef double f64x4 __attribute__((ext_vector_type(4)));

#define H      4096
#define E      64
#define TOPK   8
#define TILE_T 32

// Pre-transpose W[e][k] (f32) into the order the main loop consumes:
//   Wb[ ((m*4 + kg)*64 + e)*4 + i ] = W[e][16m + 4kg + i]
__global__ __launch_bounds__(256)
void transpose_w(const float* __restrict__ Wg, float* __restrict__ Wb)
{
  int n = blockIdx.x * 256 + threadIdx.x;    // 64*4096 = 262144
  int e = n >> 12, k = n & 4095;
  float v = Wg[n];
  int m = k >> 4, kg = (k >> 2) & 3, i = k & 3;
  Wb[(((m * 4 + kg) * 64) + e) * 4 + i] = v;
}

// f64-exact router via v_mfma_f64_16x16x4_f64 with runtime-probed fragment
// readout mapping (verified R4). This round: 512-thread blocks, K split in
// halves across wave-groups -> 4 waves/SIMD so distance-1 prefetch covers
// HBM latency (~900cy) with a ~2048cy step window.
__global__ __launch_bounds__(512)
void moe_gate_mfma(const float* __restrict__ X, const float* __restrict__ Wb,
                   float* __restrict__ out, int n_tokens)
{
  __shared__ double Ls[TILE_T * E];   // 16 KB: f64 partial-sum + epilogue

  const int tid  = threadIdx.x;
  const int lane = tid & 63;
  const int w    = tid >> 6;      // 0..7
  const int wg   = w >> 2;        // K-half: 0 -> k<2048, 1 -> k>=2048
  const int we   = w & 3;         // expert group 16we..16we+15
  const int t0   = blockIdx.x * TILE_T;
  const int l15  = lane & 15;
  const int kg   = lane >> 4;

  // ---- probe the effective (lane,reg) -> (token,expert) readout map ----
  f64x4 z = {0.0, 0.0, 0.0, 0.0};
  f64x4 pcol = __builtin_amdgcn_mfma_f64_16x16x4f64(1.0, (double)l15, z, 0, 0, 0);
  f64x4 prow = __builtin_amdgcn_mfma_f64_16x16x4f64((double)l15, 1.0, z, 0, 0, 0);
  int qrow[4], qcol[4];
  #pragma unroll
  for (int r = 0; r < 4; ++r) {
    qrow[r] = (int)(prow[r] * 0.25 + 0.5);
    qcol[r] = (int)(pcol[r] * 0.25 + 0.5);
  }

  const int kbase = wg * (H / 2);           // 0 or 2048
  const int mbase = wg * 128;               // k16-step base
  const float* xp0 = X  + (size_t)(t0 + l15) * H + kbase + 4 * kg;
  const float* xp1 = X  + (size_t)(t0 + 16 + l15) * H + kbase + 4 * kg;
  const float* bp  = Wb + (((size_t)mbase * 4 + kg) * 64 + 16 * we + l15) * 4;

  f64x4 c0 = {0.0, 0.0, 0.0, 0.0};
  f64x4 c1 = {0.0, 0.0, 0.0, 0.0};

  f32x4 a0 = *(const f32x4*)(xp0);
  f32x4 a1 = *(const f32x4*)(xp1);
  f32x4 bv = *(const f32x4*)(bp);

  #pragma unroll 4
  for (int m = 0; m < 127; ++m) {
    f32x4 na0 = *(const f32x4*)(xp0 + (m + 1) * 16);
    f32x4 na1 = *(const f32x4*)(xp1 + (m + 1) * 16);
    f32x4 nbv = *(const f32x4*)(bp + (size_t)(m + 1) * 1024);
    #pragma unroll
    for (int i = 0; i < 4; ++i) {
      double bd = (double)bv[i];
      c0 = __builtin_amdgcn_mfma_f64_16x16x4f64((double)a0[i], bd, c0, 0, 0, 0);
      c1 = __builtin_amdgcn_mfma_f64_16x16x4f64((double)a1[i], bd, c1, 0, 0, 0);
    }
    a0 = na0; a1 = na1; bv = nbv;
  }
  #pragma unroll
  for (int i = 0; i < 4; ++i) {   // last step
    double bd = (double)bv[i];
    c0 = __builtin_amdgcn_mfma_f64_16x16x4f64((double)a0[i], bd, c0, 0, 0, 0);
    c1 = __builtin_amdgcn_mfma_f64_16x16x4f64((double)a1[i], bd, c1, 0, 0, 0);
  }

  // ---- combine K-halves in LDS (low half writes, high half adds) ----
  if (wg == 0) {
    #pragma unroll
    for (int r = 0; r < 4; ++r) {
      Ls[qrow[r] * E + 16 * we + qcol[r]]        = c0[r];
      Ls[(16 + qrow[r]) * E + 16 * we + qcol[r]] = c1[r];
    }
  }
  __syncthreads();
  if (wg == 1) {
    #pragma unroll
    for (int r = 0; r < 4; ++r) {
      Ls[qrow[r] * E + 16 * we + qcol[r]]        += c0[r];
      Ls[(16 + qrow[r]) * E + 16 * we + qcol[r]] += c1[r];
    }
  }
  __syncthreads();

  // ---- per-token softmax + top-8 on f64 logits (verified R2/R4) ----
  // 8 waves x 4 tokens = 32 tokens
  for (int tt = 0; tt < 4; tt++) {
    int t = w * 4 + tt;
    double val = Ls[t * E + lane];

    double mx = val;
    #pragma unroll
    for (int off = 32; off >= 1; off >>= 1)
      mx = fmax(mx, __shfl_xor(mx, off));

    double p = exp(val - mx);
    double S = p;
    #pragma unroll
    for (int off = 32; off >= 1; off >>= 1)
      S += __shfl_xor(S, off);

    double cur = val;
    double myw = 0.0; int myidx = 0;
    double psum = 0.0;
    #pragma unroll
    for (int r = 0; r < TOPK; r++) {
      double v = cur; int ii = lane;
      #pragma unroll
      for (int off = 32; off >= 1; off >>= 1) {
        double ov = __shfl_xor(v, off);
        int    oi = __shfl_xor(ii, off);
        if (ov > v || (ov == v && oi < ii)) { v = ov; ii = oi; }
      }
      double pw = __shfl(p, ii);
      psum += pw;
      if (lane == r) { myw = pw; myidx = ii; }
      if (lane == ii) cur = -INFINITY;
    }
    double denom = psum / S + 1e-20;
    if (lane < TOPK) {
      size_t gt = (size_t)(t0 + t);
      out[gt * TOPK + lane] = (float)((myw / S) / denom);
      out[(size_t)n_tokens * TOPK + gt * TOPK + lane] = (float)myidx;
    }
  }
}

extern "C" void kernel_launch(void* const* d_in, const int* in_sizes, int n_in,
                              void* d_out, int out_size, void* d_ws, size_t ws_size,
                              hipStream_t stream)
{
  const float* X  = (const float*)d_in[0];
  const float* Wg = (const float*)d_in[1];
  float* out = (float*)d_out;
  float* Wb  = (float*)d_ws;            // 1 MB scratch
  int n_tokens = in_sizes[0] / H;       // 16384

  transpose_w<<<(E * H) / 256, 256, 0, stream>>>(Wg, Wb);
  moe_gate_mfma<<<n_tokens / TILE_T, 512, 0, stream>>>(X, Wb, out, n_tokens);
}